// Round 4
// baseline (16721.280 us; speedup 1.0000x reference)
//
#include <hip/hip_runtime.h>
#include <hip/hip_bf16.h>
#include <stdint.h>

// ---------------------------------------------------------------------------
// PFGAT: [B,T,N,F]=[4,8,2048,16] transformer (causal attn over N per (b,t),
// node attn over T-slots, MLP at last slot) -> 2x GATConv -> FFN -> [B,14,N].
// fp32 I/O (per reference dtypes), fp32 compute, bf16 intermediate storage.
// ws-adaptive: wide layout (52MiB) or narrow per-slice layout (21MiB).
// ---------------------------------------------------------------------------

#define BB     4
#define TT     8
#define NN     2048
#define FIN    16
#define HID    128
#define BM     (BB*TT)            // 32 attention slices
#define PROWS  (BM*NN)            // 65536 rows
#define NHEADS 4
#define OUTCH  64
#define OUTF   14
#define NEDGE  32768
#define NEDGEB (NEDGE*BB)         // 131072
#define NNODE  (BB*NN)            // 8192
#define NETOT  (NEDGEB + NNODE)   // 139264 (edges + self loops)

typedef __hip_bfloat16 bf16;

__device__ __forceinline__ float b2f(bf16 v){ return __bfloat162float(v); }
__device__ __forceinline__ bf16  f2b(float f){ return __float2bfloat16(f); }
__device__ __forceinline__ float bits2f(uint32_t b){ union{uint32_t u; float f;} v; v.u=b; return v.f; }

// ---------------------------------------------------------------------------
// K1: per row: LN1 over F=16 -> k,v projections (stored bf16).
// x row = in_off+blockIdx.x; K/V row = blockIdx.x (slice-local in narrow mode).
// ---------------------------------------------------------------------------
__global__ void k_kv(const float* __restrict__ x,
                     const float* __restrict__ g1, const float* __restrict__ bb1,
                     const float* __restrict__ wk, const float* __restrict__ bk,
                     const float* __restrict__ wv, const float* __restrict__ bv,
                     int in_off, bf16* __restrict__ K, bf16* __restrict__ V)
{
    const int rloc = blockIdx.x;
    const int rin  = rloc + in_off;
    const int h = threadIdx.x;       // 0..127
    __shared__ float xr[FIN], lnv[FIN];
    if (h < FIN) xr[h] = x[(size_t)rin*FIN + h];
    __syncthreads();
    float mu = 0.f;
    #pragma unroll
    for (int f = 0; f < FIN; ++f) mu += xr[f];
    mu *= (1.f/FIN);
    float var = 0.f;
    #pragma unroll
    for (int f = 0; f < FIN; ++f){ float d = xr[f]-mu; var += d*d; }
    var *= (1.f/FIN);
    const float inv = rsqrtf(var + 1e-5f);
    if (h < FIN) lnv[h] = (xr[h]-mu)*inv*g1[h] + bb1[h];
    __syncthreads();
    float ak = bk[h], av = bv[h];
    #pragma unroll
    for (int f = 0; f < FIN; ++f){
        const float l = lnv[f];
        ak += l * wk[f*HID + h];
        av += l * wv[f*HID + h];
    }
    const size_t o = (size_t)rloc*HID + h;
    K[o] = f2b(ak); V[o] = f2b(av);
}

// ---------------------------------------------------------------------------
// K2: causal attention, one block per query row i of slice (blockIdx.y+off).
// Recomputes q-row and skip-row from x, fuses ctx@t_wo + skip + t_bo epilogue,
// writes H1 (bf16).  K/V indexed by blockIdx.y (slice-local).
// ---------------------------------------------------------------------------
__global__ void k_attnT(const float* __restrict__ x,
                        const bf16* __restrict__ K, const bf16* __restrict__ V,
                        const float* __restrict__ g1, const float* __restrict__ bb1,
                        const float* __restrict__ wq, const float* __restrict__ bq,
                        const float* __restrict__ skw, const float* __restrict__ skb,
                        const float* __restrict__ t_wo, const float* __restrict__ t_bo,
                        int slice_off, bf16* __restrict__ H1)
{
    const int i     = blockIdx.x;              // query index
    const int slice = blockIdx.y + slice_off;  // absolute (b*8+t)
    const int t     = threadIdx.x;             // 0..255
    __shared__ float xr[FIN], lnv[FIN];
    __shared__ float q[HID], sk[HID], cx[HID];
    __shared__ float sc[NN];
    __shared__ float red[256];

    // ---- LN1 + q/skip projection for row i ----
    if (t < FIN) xr[t] = x[((size_t)slice*NN + i)*FIN + t];
    __syncthreads();
    float mu = 0.f;
    #pragma unroll
    for (int f = 0; f < FIN; ++f) mu += xr[f];
    mu *= (1.f/FIN);
    float var = 0.f;
    #pragma unroll
    for (int f = 0; f < FIN; ++f){ float d = xr[f]-mu; var += d*d; }
    var *= (1.f/FIN);
    const float linv = rsqrtf(var + 1e-5f);
    if (t < FIN) lnv[t] = (xr[t]-mu)*linv*g1[t] + bb1[t];
    __syncthreads();
    if (t < HID){
        float aq = bq[t], as = skb[t];
        #pragma unroll
        for (int f = 0; f < FIN; ++f){
            aq += lnv[f]*wq[f*HID + t];
            as += xr[f] *skw[f*HID + t];
        }
        q[t] = aq; sk[t] = as;
    }
    __syncthreads();

    // ---- QK^T (bf16 K, 8-elem vectorized decode) ----
    const size_t kvb = (size_t)blockIdx.y*NN*HID;
    const float scale = 0.08838834764831845f;   // 1/sqrt(128)
    for (int j = t; j <= i; j += 256){
        const uint4* kr = (const uint4*)(K + kvb + (size_t)j*HID);
        float acc = 0.f;
        #pragma unroll
        for (int c4 = 0; c4 < 16; ++c4){
            uint4 u = kr[c4];
            const int b0 = c4*8;
            acc += q[b0+0]*bits2f(u.x<<16) + q[b0+1]*bits2f(u.x & 0xffff0000u);
            acc += q[b0+2]*bits2f(u.y<<16) + q[b0+3]*bits2f(u.y & 0xffff0000u);
            acc += q[b0+4]*bits2f(u.z<<16) + q[b0+5]*bits2f(u.z & 0xffff0000u);
            acc += q[b0+6]*bits2f(u.w<<16) + q[b0+7]*bits2f(u.w & 0xffff0000u);
        }
        sc[j] = acc * scale;
    }
    __syncthreads();
    // ---- softmax over j<=i ----
    float lm = -1e30f;
    for (int j = t; j <= i; j += 256) lm = fmaxf(lm, sc[j]);
    red[t] = lm; __syncthreads();
    for (int st = 128; st > 0; st >>= 1){ if (t < st) red[t] = fmaxf(red[t], red[t+st]); __syncthreads(); }
    const float mx = red[0]; __syncthreads();
    float ls = 0.f;
    for (int j = t; j <= i; j += 256){ float e = __expf(sc[j]-mx); sc[j] = e; ls += e; }
    red[t] = ls; __syncthreads();
    for (int st = 128; st > 0; st >>= 1){ if (t < st) red[t] += red[t+st]; __syncthreads(); }
    const float pinv = 1.f / red[0];
    __syncthreads();
    // ---- PV ----
    const int h = t & (HID-1), half = t >> 7;
    float acc = 0.f;
    for (int j = half; j <= i; j += 2)
        acc += sc[j] * b2f(V[kvb + (size_t)j*HID + h]);
    red[t] = acc; __syncthreads();
    if (t < HID) cx[t] = (red[t] + red[t+HID]) * pinv;
    __syncthreads();
    // ---- epilogue: H1 = skip + ctx@t_wo + t_bo ----
    if (t < HID){
        float o = sk[t] + t_bo[t];
        for (int c = 0; c < HID; ++c) o += cx[c]*t_wo[c*HID + t];
        H1[((size_t)slice*NN + i)*HID + t] = f2b(o);
    }
}

// ---------------------------------------------------------------------------
// K3: per (b,s): load h1[m] (all 8 m), LN2, node attention (q for m=7 only),
// LN3, MLP -> node feature [128] fp32.
// ---------------------------------------------------------------------------
__global__ void k_mix(const bf16* __restrict__ H1,
                      const float* __restrict__ ln2g, const float* __restrict__ ln2b,
                      const float* __restrict__ s_wq, const float* __restrict__ s_bq,
                      const float* __restrict__ s_wk, const float* __restrict__ s_bk,
                      const float* __restrict__ s_wv, const float* __restrict__ s_bv,
                      const float* __restrict__ s_wo, const float* __restrict__ s_bo,
                      const float* __restrict__ ln3g, const float* __restrict__ ln3b,
                      const float* __restrict__ w1, const float* __restrict__ bm1,
                      const float* __restrict__ w2, const float* __restrict__ bm2,
                      float* __restrict__ Hn)
{
    const int blk = blockIdx.x;          // b*NN + s
    const int b = blk >> 11, s = blk & (NN-1);
    const int h = threadIdx.x;           // 0..127
    __shared__ float h1[TT][HID], z2[TT][HID], k2[TT][HID], v2[TT][HID];
    __shared__ float qv[HID], z3s[HID], hls[2*HID];
    __shared__ float scr[TT];
    __shared__ float rb1[HID], rb2[HID];

    #pragma unroll
    for (int m = 0; m < TT; ++m)
        h1[m][h] = b2f(H1[((size_t)(b*TT + m)*NN + s)*HID + h]);
    __syncthreads();

    // LN2 each row -> z2
    const float g2v = ln2g[h], b2v = ln2b[h];
    for (int m = 0; m < TT; ++m){
        const float v = h1[m][h];
        rb1[h] = v; rb2[h] = v*v; __syncthreads();
        for (int st = 64; st > 0; st >>= 1){
            if (h < st){ rb1[h] += rb1[h+st]; rb2[h] += rb2[h+st]; }
            __syncthreads();
        }
        const float mu = rb1[0]*(1.f/HID);
        const float var = rb2[0]*(1.f/HID) - mu*mu;
        const float inv = rsqrtf(var + 1e-5f);
        __syncthreads();
        z2[m][h] = (v - mu)*inv*g2v + b2v;
    }
    __syncthreads();

    // k2, v2 for all m; q for m=7 only
    {
        float ack[TT], acv[TT];
        const float bkv = s_bk[h], bvv = s_bv[h];
        #pragma unroll
        for (int m = 0; m < TT; ++m){ ack[m] = bkv; acv[m] = bvv; }
        for (int c = 0; c < HID; ++c){
            const float wk = s_wk[c*HID + h];
            const float wv = s_wv[c*HID + h];
            #pragma unroll
            for (int m = 0; m < TT; ++m){ ack[m] += z2[m][c]*wk; acv[m] += z2[m][c]*wv; }
        }
        #pragma unroll
        for (int m = 0; m < TT; ++m){ k2[m][h] = ack[m]; v2[m][h] = acv[m]; }
        float aq = s_bq[h];
        for (int c = 0; c < HID; ++c) aq += z2[TT-1][c]*s_wq[c*HID + h];
        qv[h] = aq;
    }
    __syncthreads();

    if (h < TT){
        float d = 0.f;
        for (int c = 0; c < HID; ++c) d += qv[c]*k2[h][c];
        scr[h] = d * 0.08838834764831845f;
    }
    __syncthreads();
    float mx = -1e30f;
    #pragma unroll
    for (int m = 0; m < TT; ++m) mx = fmaxf(mx, scr[m]);
    float p[TT], se = 0.f;
    #pragma unroll
    for (int m = 0; m < TT; ++m){ p[m] = __expf(scr[m]-mx); se += p[m]; }
    const float isum = 1.f/se;
    float c2 = 0.f;
    #pragma unroll
    for (int m = 0; m < TT; ++m) c2 += p[m]*v2[m][h];
    c2 *= isum;
    __syncthreads();
    qv[h] = c2;          // reuse qv as ctx2
    __syncthreads();

    float o = s_bo[h];
    for (int c = 0; c < HID; ++c) o += qv[c]*s_wo[c*HID + h];
    const float h2 = h1[TT-1][h] + o;

    // LN3
    rb1[h] = h2; rb2[h] = h2*h2; __syncthreads();
    for (int st = 64; st > 0; st >>= 1){
        if (h < st){ rb1[h] += rb1[h+st]; rb2[h] += rb2[h+st]; }
        __syncthreads();
    }
    {
        const float mu = rb1[0]*(1.f/HID);
        const float var = rb2[0]*(1.f/HID) - mu*mu;
        const float inv = rsqrtf(var + 1e-5f);
        __syncthreads();
        z3s[h] = (h2 - mu)*inv*ln3g[h] + ln3b[h];
    }
    __syncthreads();

    float hid0 = bm1[h], hid1 = bm1[h+HID];
    for (int c = 0; c < HID; ++c){
        const float z = z3s[c];
        hid0 += z * w1[c*2*HID + h];
        hid1 += z * w1[c*2*HID + h + HID];
    }
    hls[h] = fmaxf(hid0, 0.f); hls[h+HID] = fmaxf(hid1, 0.f);
    __syncthreads();
    float outv = bm2[h] + h2;
    for (int j = 0; j < 2*HID; ++j) outv += hls[j]*w2[j*HID + h];
    Hn[(size_t)(b*NN + s)*HID + h] = outv;
}

// ---------------------------------------------------------------------------
// GAT
// ---------------------------------------------------------------------------
__device__ __forceinline__ void edge_decode(const int* __restrict__ ei, int e,
                                            int& src, int& dst, bool& dropped)
{
    if (e < NEDGEB){
        const int bb = e >> 15, k = e & (NEDGE-1);
        const int s0 = ei[k], d0 = ei[NEDGE + k];
        src = s0 + bb*NN; dst = d0 + bb*NN;
        dropped = (s0 == d0);     // PyG removes pre-existing self loops
    } else { src = dst = e - NEDGEB; dropped = false; }
}

__global__ void k_gat1_lin(const float* __restrict__ Hn, const float* __restrict__ W,
                           const float* __restrict__ asrc, const float* __restrict__ adst,
                           bf16* __restrict__ hw, float* __restrict__ als, float* __restrict__ ald)
{
    const int nid = blockIdx.x, c = threadIdx.x;   // 128
    __shared__ float hr[HID], r1[HID], r2[HID];
    hr[c] = Hn[(size_t)nid*HID + c];
    __syncthreads();
    float a = 0.f;
    for (int k = 0; k < HID; ++k) a += hr[k]*W[k*HID + c];
    hw[(size_t)nid*HID + c] = f2b(a);
    r1[c] = a*asrc[c]; r2[c] = a*adst[c];
    __syncthreads();
    for (int st = 16; st > 0; st >>= 1){
        if ((c & 31) < st){ r1[c] += r1[c+st]; r2[c] += r2[c+st]; }
        __syncthreads();
    }
    if ((c & 31) == 0){
        als[nid*NHEADS + (c>>5)] = r1[c];
        ald[nid*NHEADS + (c>>5)] = r2[c];
    }
}

// exp(alpha) + segment-sum denom (segment-max skipped: shift-invariant,
// alphas are O(0.3) -> no overflow risk).
__global__ void k_gat_edge1(const int* __restrict__ ei, const float* __restrict__ als,
                            const float* __restrict__ ald, bf16* __restrict__ ex,
                            float* __restrict__ denom)
{
    const int idx = blockIdx.x*blockDim.x + threadIdx.x;
    if (idx >= NETOT*NHEADS) return;
    const int e = idx >> 2, hd = idx & 3;
    int src, dst; bool drop;
    edge_decode(ei, e, src, dst, drop);
    if (drop){ ex[idx] = f2b(0.f); return; }
    float a = als[src*NHEADS + hd] + ald[dst*NHEADS + hd];
    a = a > 0.f ? a : 0.2f*a;
    const bf16 vb = f2b(__expf(a));
    ex[idx] = vb;
    atomicAdd(&denom[dst*NHEADS + hd], b2f(vb));
}

__global__ void k_gat_agg1(const int* __restrict__ ei, const bf16* __restrict__ ex,
                           const float* __restrict__ denom, const bf16* __restrict__ hw,
                           float* __restrict__ agg)
{
    const int t = blockIdx.x*blockDim.x + threadIdx.x;   // NETOT*128
    const int e = t >> 7, c = t & 127;
    if (e >= NETOT) return;
    const float x = b2f(ex[e*NHEADS + (c>>5)]);
    if (x == 0.f) return;
    int src, dst; bool drop;
    edge_decode(ei, e, src, dst, drop);
    const float w = x / denom[dst*NHEADS + (c>>5)];
    atomicAdd(&agg[(size_t)dst*HID + c], w * b2f(hw[(size_t)src*HID + c]));
}

__global__ void k_gat1_fin(const float* __restrict__ agg, const float* __restrict__ bias,
                           bf16* __restrict__ g1)
{
    const int t = blockIdx.x*blockDim.x + threadIdx.x;
    if (t >= NNODE*HID) return;
    const float v = agg[t] + bias[t & 127];
    g1[t] = f2b(v > 0.f ? v : expm1f(v));    // elu
}

__global__ void k_gat2_lin(const bf16* __restrict__ g1, const float* __restrict__ W,
                           const float* __restrict__ asrc, const float* __restrict__ adst,
                           bf16* __restrict__ hw2, float* __restrict__ al2s, float* __restrict__ al2d)
{
    const int nid = blockIdx.x, c = threadIdx.x;    // 64 threads = 1 wave
    __shared__ float hr[HID];
    hr[c] = b2f(g1[(size_t)nid*HID + c]);
    hr[c+64] = b2f(g1[(size_t)nid*HID + c + 64]);
    __syncthreads();
    float a = 0.f;
    for (int k = 0; k < HID; ++k) a += hr[k]*W[k*OUTCH + c];
    hw2[(size_t)nid*OUTCH + c] = f2b(a);
    float s1 = a*asrc[c], s2 = a*adst[c];
    #pragma unroll
    for (int off = 32; off > 0; off >>= 1){
        s1 += __shfl_down(s1, off);
        s2 += __shfl_down(s2, off);
    }
    if (c == 0){ al2s[nid] = s1; al2d[nid] = s2; }
}

__global__ void k_gat_edge2(const int* __restrict__ ei, const float* __restrict__ als,
                            const float* __restrict__ ald, bf16* __restrict__ ex,
                            float* __restrict__ denom)
{
    const int e = blockIdx.x*blockDim.x + threadIdx.x;
    if (e >= NETOT) return;
    int src, dst; bool drop;
    edge_decode(ei, e, src, dst, drop);
    if (drop){ ex[e] = f2b(0.f); return; }
    float a = als[src] + ald[dst];
    a = a > 0.f ? a : 0.2f*a;
    const bf16 vb = f2b(__expf(a));
    ex[e] = vb;
    atomicAdd(&denom[dst], b2f(vb));
}

__global__ void k_gat_agg2(const int* __restrict__ ei, const bf16* __restrict__ ex,
                           const float* __restrict__ denom, const bf16* __restrict__ hw2,
                           float* __restrict__ agg)
{
    const int t = blockIdx.x*blockDim.x + threadIdx.x;   // NETOT*64
    const int e = t >> 6, c = t & 63;
    if (e >= NETOT) return;
    const float x = b2f(ex[e]);
    if (x == 0.f) return;
    int src, dst; bool drop;
    edge_decode(ei, e, src, dst, drop);
    const float w = x / denom[dst];
    atomicAdd(&agg[(size_t)dst*OUTCH + c], w * b2f(hw2[(size_t)src*OUTCH + c]));
}

__global__ void k_final(const float* __restrict__ agg2, const float* __restrict__ g2b,
                        const float* __restrict__ fw, const float* __restrict__ fb,
                        float* __restrict__ out)
{
    const int nid = blockIdx.x, c = threadIdx.x;    // 64
    __shared__ float g[OUTCH];
    g[c] = agg2[(size_t)nid*OUTCH + c] + g2b[c];
    __syncthreads();
    if (c < OUTF){
        float o = fb[c];
        for (int k = 0; k < OUTCH; ++k) o += g[k]*fw[k*OUTF + c];
        const int b = nid >> 11, n = nid & (NN-1);
        out[((size_t)b*OUTF + c)*NN + n] = o;
    }
}

// ---------------------------------------------------------------------------
extern "C" void kernel_launch(void* const* d_in, const int* in_sizes, int n_in,
                              void* d_out, int out_size, void* d_ws, size_t ws_size,
                              hipStream_t stream)
{
    const float* x    = (const float*)d_in[0];
    const int*  ei    = (const int*)d_in[1];
    const float* ln1g = (const float*)d_in[2];  const float* ln1b = (const float*)d_in[3];
    const float* t_wq = (const float*)d_in[4];  const float* t_bq = (const float*)d_in[5];
    const float* t_wk = (const float*)d_in[6];  const float* t_bk = (const float*)d_in[7];
    const float* t_wv = (const float*)d_in[8];  const float* t_bv = (const float*)d_in[9];
    const float* t_wo = (const float*)d_in[10]; const float* t_bo = (const float*)d_in[11];
    const float* skw  = (const float*)d_in[12]; const float* skb  = (const float*)d_in[13];
    const float* ln2g = (const float*)d_in[14]; const float* ln2b = (const float*)d_in[15];
    const float* s_wq = (const float*)d_in[16]; const float* s_bq = (const float*)d_in[17];
    const float* s_wk = (const float*)d_in[18]; const float* s_bk = (const float*)d_in[19];
    const float* s_wv = (const float*)d_in[20]; const float* s_bv = (const float*)d_in[21];
    const float* s_wo = (const float*)d_in[22]; const float* s_bo = (const float*)d_in[23];
    const float* ln3g = (const float*)d_in[24]; const float* ln3b = (const float*)d_in[25];
    const float* w1   = (const float*)d_in[26]; const float* b1   = (const float*)d_in[27];
    const float* w2   = (const float*)d_in[28]; const float* b2   = (const float*)d_in[29];
    const float* g1w  = (const float*)d_in[30];
    const float* g1as = (const float*)d_in[31]; const float* g1ad = (const float*)d_in[32];
    const float* g1b  = (const float*)d_in[33];
    const float* g2w  = (const float*)d_in[34];
    const float* g2as = (const float*)d_in[35]; const float* g2ad = (const float*)d_in[36];
    const float* g2b  = (const float*)d_in[37];
    const float* ffw  = (const float*)d_in[38]; const float* ffb  = (const float*)d_in[39];
    float* out = (float*)d_out;

    const size_t MiB = 1024u*1024u;
    const bool wide = ws_size >= 52*MiB;   // K(16)+V(16)+H1(16)+Hn(4)

    char* base = (char*)d_ws;
    bf16 *Kb, *Vb, *H1;
    float* Hn;
    char* gat_base;
    if (wide){
        Kb = (bf16*)(base + 0*MiB);        // 16 MiB (all 32 slices)
        Vb = (bf16*)(base + 16*MiB);       // 16 MiB
        H1 = (bf16*)(base + 32*MiB);       // 16 MiB
        Hn = (float*)(base + 48*MiB);      // 4 MiB
        gat_base = base;                   // aliases Kb/Vb (dead after attn)
    } else {
        H1 = (bf16*)(base + 0*MiB);        // 16 MiB
        Hn = (float*)(base + 16*MiB);      // 4 MiB
        Kb = (bf16*)(base + 20*MiB);       // 0.5 MiB (one slice)
        Vb = (bf16*)(base + 20*MiB + 512u*1024u);
        gat_base = base;                   // aliases H1 (dead after k_mix)
    }
    // GAT scratch (~12.9 MiB) inside gat_base
    char* w = gat_base;
    auto alloc = [&](size_t bytes){ void* p = (void*)w; w += (bytes + 255) & ~(size_t)255; return p; };
    bf16*  hw1  = (bf16*) alloc((size_t)NNODE*HID*sizeof(bf16));
    float* als1 = (float*)alloc((size_t)NNODE*NHEADS*sizeof(float));
    float* ald1 = (float*)alloc((size_t)NNODE*NHEADS*sizeof(float));
    bf16*  ex1  = (bf16*) alloc((size_t)NETOT*NHEADS*sizeof(bf16));
    float* den1 = (float*)alloc((size_t)NNODE*NHEADS*sizeof(float));
    float* agg1 = (float*)alloc((size_t)NNODE*HID*sizeof(float));
    bf16*  g1o  = (bf16*) alloc((size_t)NNODE*HID*sizeof(bf16));
    bf16*  hw2  = (bf16*) alloc((size_t)NNODE*OUTCH*sizeof(bf16));
    float* als2 = (float*)alloc((size_t)NNODE*sizeof(float));
    float* ald2 = (float*)alloc((size_t)NNODE*sizeof(float));
    bf16*  ex2  = (bf16*) alloc((size_t)NETOT*sizeof(bf16));
    float* den2 = (float*)alloc((size_t)NNODE*sizeof(float));
    float* agg2 = (float*)alloc((size_t)NNODE*OUTCH*sizeof(float));

    // ---- trunk ----
    if (wide){
        k_kv<<<PROWS, HID, 0, stream>>>(x, ln1g, ln1b, t_wk, t_bk, t_wv, t_bv, 0, Kb, Vb);
        k_attnT<<<dim3(NN, BM), 256, 0, stream>>>(x, Kb, Vb, ln1g, ln1b, t_wq, t_bq,
                                                  skw, skb, t_wo, t_bo, 0, H1);
    } else {
        for (int s = 0; s < BM; ++s){
            k_kv<<<NN, HID, 0, stream>>>(x, ln1g, ln1b, t_wk, t_bk, t_wv, t_bv, s*NN, Kb, Vb);
            k_attnT<<<dim3(NN, 1), 256, 0, stream>>>(x, Kb, Vb, ln1g, ln1b, t_wq, t_bq,
                                                     skw, skb, t_wo, t_bo, s, H1);
        }
    }
    k_mix<<<BB*NN, HID, 0, stream>>>(H1, ln2g, ln2b, s_wq, s_bq, s_wk, s_bk,
                                     s_wv, s_bv, s_wo, s_bo, ln3g, ln3b,
                                     w1, b1, w2, b2, Hn);

    // ---- GAT (accumulators zeroed after k_mix; region was dead/poisoned) ----
    hipMemsetAsync(den1, 0, (size_t)NNODE*NHEADS*sizeof(float), stream);
    hipMemsetAsync(agg1, 0, (size_t)NNODE*HID*sizeof(float), stream);
    hipMemsetAsync(den2, 0, (size_t)NNODE*sizeof(float), stream);
    hipMemsetAsync(agg2, 0, (size_t)NNODE*OUTCH*sizeof(float), stream);

    k_gat1_lin<<<NNODE, HID, 0, stream>>>(Hn, g1w, g1as, g1ad, hw1, als1, ald1);
    k_gat_edge1<<<(NETOT*NHEADS + 255)/256, 256, 0, stream>>>(ei, als1, ald1, ex1, den1);
    k_gat_agg1<<<(NETOT*HID)/256, 256, 0, stream>>>(ei, ex1, den1, hw1, agg1);
    k_gat1_fin<<<(NNODE*HID)/256, 256, 0, stream>>>(agg1, g1b, g1o);
    k_gat2_lin<<<NNODE, OUTCH, 0, stream>>>(g1o, g2w, g2as, g2ad, hw2, als2, ald2);
    k_gat_edge2<<<(NETOT + 255)/256, 256, 0, stream>>>(ei, als2, ald2, ex2, den2);
    k_gat_agg2<<<(NETOT*OUTCH)/256, 256, 0, stream>>>(ei, ex2, den2, hw2, agg2);
    k_final<<<NNODE, OUTCH, 0, stream>>>(agg2, g2b, ffw, ffb, out);
}

// Round 5
// 5537.821 us; speedup vs baseline: 3.0195x; 3.0195x over previous
//
#include <hip/hip_runtime.h>
#include <hip/hip_bf16.h>
#include <stdint.h>

// ---------------------------------------------------------------------------
// PFGAT: [B,T,N,F]=[4,8,2048,16] transformer (causal attn over N per (b,t),
// node attn over T-slots, MLP at last slot) -> 2x GATConv -> FFN -> [B,14,N].
// fp32 I/O, fp32 compute, bf16 intermediate storage.
// R5: flash-tiled causal attention (Q-tile 64, K-tile 32, online softmax),
// K/V staged once per block -> HBM traffic 34GB -> ~1GB.
// ---------------------------------------------------------------------------

#define BB     4
#define TT     8
#define NN     2048
#define FIN    16
#define HID    128
#define BM     (BB*TT)            // 32 attention slices
#define PROWS  (BM*NN)            // 65536 rows
#define NHEADS 4
#define OUTCH  64
#define OUTF   14
#define NEDGE  32768
#define NEDGEB (NEDGE*BB)         // 131072
#define NNODE  (BB*NN)            // 8192
#define NETOT  (NEDGEB + NNODE)   // 139264 (edges + self loops)

#define TQ     64                 // query tile
#define TK     32                 // key tile

typedef __hip_bfloat16 bf16;

__device__ __forceinline__ float b2f(bf16 v){ return __bfloat162float(v); }
__device__ __forceinline__ bf16  f2b(float f){ return __float2bfloat16(f); }
__device__ __forceinline__ float bits2f(uint32_t b){ union{uint32_t u; float f;} v; v.u=b; return v.f; }

// ---------------------------------------------------------------------------
// K1: per row: LN1 over F=16 -> k,v projections (stored bf16).
// ---------------------------------------------------------------------------
__global__ void k_kv(const float* __restrict__ x,
                     const float* __restrict__ g1, const float* __restrict__ bb1,
                     const float* __restrict__ wk, const float* __restrict__ bk,
                     const float* __restrict__ wv, const float* __restrict__ bv,
                     int in_off, bf16* __restrict__ K, bf16* __restrict__ V)
{
    const int rloc = blockIdx.x;
    const int rin  = rloc + in_off;
    const int h = threadIdx.x;       // 0..127
    __shared__ float xr[FIN], lnv[FIN];
    if (h < FIN) xr[h] = x[(size_t)rin*FIN + h];
    __syncthreads();
    float mu = 0.f;
    #pragma unroll
    for (int f = 0; f < FIN; ++f) mu += xr[f];
    mu *= (1.f/FIN);
    float var = 0.f;
    #pragma unroll
    for (int f = 0; f < FIN; ++f){ float d = xr[f]-mu; var += d*d; }
    var *= (1.f/FIN);
    const float inv = rsqrtf(var + 1e-5f);
    if (h < FIN) lnv[h] = (xr[h]-mu)*inv*g1[h] + bb1[h];
    __syncthreads();
    float ak = bk[h], av = bv[h];
    #pragma unroll
    for (int f = 0; f < FIN; ++f){
        const float l = lnv[f];
        ak += l * wk[f*HID + h];
        av += l * wv[f*HID + h];
    }
    const size_t o = (size_t)rloc*HID + h;
    K[o] = f2b(ak); V[o] = f2b(av);
}

// ---------------------------------------------------------------------------
// K2 (flash): one block = (64-query tile, slice). 256 threads = (qr 0..63,
// cg 0..3); thread owns 32 channels of one query row. K/V tiles (32x128)
// staged to LDS as fp32; online softmax in registers; fused epilogue
// H1 = skip + ctx@t_wo + t_bo.  K/V indexed slice-local via blockIdx.y.
// ---------------------------------------------------------------------------
__global__ __launch_bounds__(256)
void k_attn_flash(const float* __restrict__ x,
                  const bf16* __restrict__ K, const bf16* __restrict__ V,
                  const float* __restrict__ g1, const float* __restrict__ bb1,
                  const float* __restrict__ wq, const float* __restrict__ bq,
                  const float* __restrict__ skw, const float* __restrict__ skb,
                  const float* __restrict__ t_wo, const float* __restrict__ t_bo,
                  int slice_off, bf16* __restrict__ H1)
{
    const int q0    = blockIdx.x * TQ;
    const int slice = blockIdx.y + slice_off;   // absolute slice for x/H1
    const int t  = threadIdx.x;
    const int qr = t >> 2;            // query row in tile 0..63
    const int cg = t & 3;             // channel group
    const int c0 = cg * 32;
    const int qi = q0 + qr;           // global query index

    __shared__ float xs [TQ][FIN];    // raw x rows (for skip)
    __shared__ float lns[TQ][FIN];    // LN1(x) rows (for q)
    __shared__ float kv [2*TK*HID];   // K tile | V tile (fp32); cx after loop

    // ---- stage x rows ----
    for (int u = t; u < TQ*FIN; u += 256)
        ((float*)xs)[u] = x[((size_t)slice*NN + q0)*FIN + u];
    __syncthreads();
    // ---- LN1 per row (64 rows, thread t<64 does row t) ----
    if (t < TQ){
        float mu = 0.f;
        #pragma unroll
        for (int f = 0; f < FIN; ++f) mu += xs[t][f];
        mu *= (1.f/FIN);
        float var = 0.f;
        #pragma unroll
        for (int f = 0; f < FIN; ++f){ float d = xs[t][f]-mu; var += d*d; }
        var *= (1.f/FIN);
        const float inv = rsqrtf(var + 1e-5f);
        #pragma unroll
        for (int f = 0; f < FIN; ++f)
            lns[t][f] = (xs[t][f]-mu)*inv*g1[f] + bb1[f];
    }
    __syncthreads();

    // ---- q slice (scale folded in) into registers ----
    float qreg[32];
    {
        const float scale = 0.08838834764831845f;   // 1/sqrt(128)
        #pragma unroll
        for (int k = 0; k < 32; ++k){
            const int ch = c0 + k;
            float a = bq[ch];
            #pragma unroll
            for (int f = 0; f < FIN; ++f) a += lns[qr][f]*wq[f*HID + ch];
            qreg[k] = a * scale;
        }
    }

    float O[32];
    #pragma unroll
    for (int k = 0; k < 32; ++k) O[k] = 0.f;
    float m = -1e30f, l = 0.f;

    const size_t kvb = (size_t)blockIdx.y * NN * HID;   // slice-local K/V
    const int jmax = q0 + TQ - 1;

    for (int j0 = 0; j0 <= jmax; j0 += TK){
        // ---- stage K,V tile -> fp32 LDS (decode once) ----
        {
            const uint4* ks = (const uint4*)(K + kvb + (size_t)j0*HID);
            const uint4* vs = (const uint4*)(V + kvb + (size_t)j0*HID);
            #pragma unroll
            for (int r = 0; r < 2; ++r){
                const int idx = t + r*256;          // uint4 index, 512 total
                uint4 u = ks[idx];
                float* d = &kv[idx*8];
                d[0]=bits2f(u.x<<16); d[1]=bits2f(u.x&0xffff0000u);
                d[2]=bits2f(u.y<<16); d[3]=bits2f(u.y&0xffff0000u);
                d[4]=bits2f(u.z<<16); d[5]=bits2f(u.z&0xffff0000u);
                d[6]=bits2f(u.w<<16); d[7]=bits2f(u.w&0xffff0000u);
                uint4 w = vs[idx];
                float* dv = &kv[TK*HID + idx*8];
                dv[0]=bits2f(w.x<<16); dv[1]=bits2f(w.x&0xffff0000u);
                dv[2]=bits2f(w.y<<16); dv[3]=bits2f(w.y&0xffff0000u);
                dv[4]=bits2f(w.z<<16); dv[5]=bits2f(w.z&0xffff0000u);
                dv[6]=bits2f(w.w<<16); dv[7]=bits2f(w.w&0xffff0000u);
            }
        }
        __syncthreads();

        // ---- scores (partial dot over 32 ch, butterfly over cg) ----
        int jlim = qi - j0 + 1;                 // #valid keys in this tile
        if (jlim > TK) jlim = TK;
        float S[TK];
        #pragma unroll
        for (int j = 0; j < TK; ++j){
            const float* kr = &kv[j*HID + c0];
            float a = 0.f;
            #pragma unroll
            for (int k = 0; k < 32; ++k) a += qreg[k]*kr[k];
            a += __shfl_xor(a, 1);
            a += __shfl_xor(a, 2);
            S[j] = (j < jlim) ? a : -1e30f;
        }
        // ---- online softmax update ----
        float tm = m;
        #pragma unroll
        for (int j = 0; j < TK; ++j) tm = fmaxf(tm, S[j]);
        const float alpha = __expf(m - tm);
        m = tm;
        float ss = 0.f;
        #pragma unroll
        for (int j = 0; j < TK; ++j){ S[j] = __expf(S[j]-tm); ss += S[j]; }
        l = l*alpha + ss;
        #pragma unroll
        for (int k = 0; k < 32; ++k) O[k] *= alpha;
        #pragma unroll
        for (int j = 0; j < TK; ++j){
            const float p = S[j];
            const float* vr = &kv[TK*HID + j*HID + c0];
            #pragma unroll
            for (int k = 0; k < 32; ++k) O[k] += p*vr[k];
        }
        __syncthreads();    // kv dead, next tile may overwrite
    }

    // ---- ctx -> LDS (reuse kv: TQ*HID fp32 = 32 KiB exactly) ----
    {
        const float linv = 1.f/l;
        float* cx = kv;
        #pragma unroll
        for (int k = 0; k < 32; ++k) cx[qr*HID + c0 + k] = O[k]*linv;
    }
    __syncthreads();

    // ---- epilogue: H1 = skip + ctx@t_wo + t_bo ----
    {
        const float* cx = kv;
        float out[32];
        #pragma unroll
        for (int k = 0; k < 32; ++k){
            const int ch = c0 + k;
            float a = t_bo[ch] + skb[ch];
            #pragma unroll
            for (int f = 0; f < FIN; ++f) a += xs[qr][f]*skw[f*HID + ch];
            out[k] = a;
        }
        for (int c = 0; c < HID; ++c){
            const float cxv = cx[qr*HID + c];
            #pragma unroll
            for (int k = 0; k < 32; ++k) out[k] += cxv * t_wo[c*HID + c0 + k];
        }
        #pragma unroll
        for (int k = 0; k < 32; ++k)
            H1[((size_t)slice*NN + qi)*HID + c0 + k] = f2b(out[k]);
    }
}

// ---------------------------------------------------------------------------
// K3: per (b,s): load h1[m] (all 8 m), LN2, node attention (q for m=7 only),
// LN3, MLP -> node feature [128] fp32.
// ---------------------------------------------------------------------------
__global__ void k_mix(const bf16* __restrict__ H1,
                      const float* __restrict__ ln2g, const float* __restrict__ ln2b,
                      const float* __restrict__ s_wq, const float* __restrict__ s_bq,
                      const float* __restrict__ s_wk, const float* __restrict__ s_bk,
                      const float* __restrict__ s_wv, const float* __restrict__ s_bv,
                      const float* __restrict__ s_wo, const float* __restrict__ s_bo,
                      const float* __restrict__ ln3g, const float* __restrict__ ln3b,
                      const float* __restrict__ w1, const float* __restrict__ bm1,
                      const float* __restrict__ w2, const float* __restrict__ bm2,
                      float* __restrict__ Hn)
{
    const int blk = blockIdx.x;          // b*NN + s
    const int b = blk >> 11, s = blk & (NN-1);
    const int h = threadIdx.x;           // 0..127
    __shared__ float h1[TT][HID], z2[TT][HID], k2[TT][HID], v2[TT][HID];
    __shared__ float qv[HID], z3s[HID], hls[2*HID];
    __shared__ float scr[TT];
    __shared__ float rb1[HID], rb2[HID];

    #pragma unroll
    for (int m = 0; m < TT; ++m)
        h1[m][h] = b2f(H1[((size_t)(b*TT + m)*NN + s)*HID + h]);
    __syncthreads();

    // LN2 each row -> z2
    const float g2v = ln2g[h], b2v = ln2b[h];
    for (int m = 0; m < TT; ++m){
        const float v = h1[m][h];
        rb1[h] = v; rb2[h] = v*v; __syncthreads();
        for (int st = 64; st > 0; st >>= 1){
            if (h < st){ rb1[h] += rb1[h+st]; rb2[h] += rb2[h+st]; }
            __syncthreads();
        }
        const float mu = rb1[0]*(1.f/HID);
        const float var = rb2[0]*(1.f/HID) - mu*mu;
        const float inv = rsqrtf(var + 1e-5f);
        __syncthreads();
        z2[m][h] = (v - mu)*inv*g2v + b2v;
    }
    __syncthreads();

    // k2, v2 for all m; q for m=7 only
    {
        float ack[TT], acv[TT];
        const float bkv = s_bk[h], bvv = s_bv[h];
        #pragma unroll
        for (int m = 0; m < TT; ++m){ ack[m] = bkv; acv[m] = bvv; }
        for (int c = 0; c < HID; ++c){
            const float wk = s_wk[c*HID + h];
            const float wv = s_wv[c*HID + h];
            #pragma unroll
            for (int m = 0; m < TT; ++m){ ack[m] += z2[m][c]*wk; acv[m] += z2[m][c]*wv; }
        }
        #pragma unroll
        for (int m = 0; m < TT; ++m){ k2[m][h] = ack[m]; v2[m][h] = acv[m]; }
        float aq = s_bq[h];
        for (int c = 0; c < HID; ++c) aq += z2[TT-1][c]*s_wq[c*HID + h];
        qv[h] = aq;
    }
    __syncthreads();

    if (h < TT){
        float d = 0.f;
        for (int c = 0; c < HID; ++c) d += qv[c]*k2[h][c];
        scr[h] = d * 0.08838834764831845f;
    }
    __syncthreads();
    float mx = -1e30f;
    #pragma unroll
    for (int m = 0; m < TT; ++m) mx = fmaxf(mx, scr[m]);
    float p[TT], se = 0.f;
    #pragma unroll
    for (int m = 0; m < TT; ++m){ p[m] = __expf(scr[m]-mx); se += p[m]; }
    const float isum = 1.f/se;
    float c2 = 0.f;
    #pragma unroll
    for (int m = 0; m < TT; ++m) c2 += p[m]*v2[m][h];
    c2 *= isum;
    __syncthreads();
    qv[h] = c2;          // reuse qv as ctx2
    __syncthreads();

    float o = s_bo[h];
    for (int c = 0; c < HID; ++c) o += qv[c]*s_wo[c*HID + h];
    const float h2 = h1[TT-1][h] + o;

    // LN3
    rb1[h] = h2; rb2[h] = h2*h2; __syncthreads();
    for (int st = 64; st > 0; st >>= 1){
        if (h < st){ rb1[h] += rb1[h+st]; rb2[h] += rb2[h+st]; }
        __syncthreads();
    }
    {
        const float mu = rb1[0]*(1.f/HID);
        const float var = rb2[0]*(1.f/HID) - mu*mu;
        const float inv = rsqrtf(var + 1e-5f);
        __syncthreads();
        z3s[h] = (h2 - mu)*inv*ln3g[h] + ln3b[h];
    }
    __syncthreads();

    float hid0 = bm1[h], hid1 = bm1[h+HID];
    for (int c = 0; c < HID; ++c){
        const float z = z3s[c];
        hid0 += z * w1[c*2*HID + h];
        hid1 += z * w1[c*2*HID + h + HID];
    }
    hls[h] = fmaxf(hid0, 0.f); hls[h+HID] = fmaxf(hid1, 0.f);
    __syncthreads();
    float outv = bm2[h] + h2;
    for (int j = 0; j < 2*HID; ++j) outv += hls[j]*w2[j*HID + h];
    Hn[(size_t)(b*NN + s)*HID + h] = outv;
}

// ---------------------------------------------------------------------------
// GAT
// ---------------------------------------------------------------------------
__device__ __forceinline__ void edge_decode(const int* __restrict__ ei, int e,
                                            int& src, int& dst, bool& dropped)
{
    if (e < NEDGEB){
        const int bb = e >> 15, k = e & (NEDGE-1);
        const int s0 = ei[k], d0 = ei[NEDGE + k];
        src = s0 + bb*NN; dst = d0 + bb*NN;
        dropped = (s0 == d0);     // PyG removes pre-existing self loops
    } else { src = dst = e - NEDGEB; dropped = false; }
}

__global__ void k_gat1_lin(const float* __restrict__ Hn, const float* __restrict__ W,
                           const float* __restrict__ asrc, const float* __restrict__ adst,
                           bf16* __restrict__ hw, float* __restrict__ als, float* __restrict__ ald)
{
    const int nid = blockIdx.x, c = threadIdx.x;   // 128
    __shared__ float hr[HID], r1[HID], r2[HID];
    hr[c] = Hn[(size_t)nid*HID + c];
    __syncthreads();
    float a = 0.f;
    for (int k = 0; k < HID; ++k) a += hr[k]*W[k*HID + c];
    hw[(size_t)nid*HID + c] = f2b(a);
    r1[c] = a*asrc[c]; r2[c] = a*adst[c];
    __syncthreads();
    for (int st = 16; st > 0; st >>= 1){
        if ((c & 31) < st){ r1[c] += r1[c+st]; r2[c] += r2[c+st]; }
        __syncthreads();
    }
    if ((c & 31) == 0){
        als[nid*NHEADS + (c>>5)] = r1[c];
        ald[nid*NHEADS + (c>>5)] = r2[c];
    }
}

// exp(alpha) + segment-sum denom (segment-max skipped: shift-invariant,
// alphas are O(0.3) -> no overflow risk).
__global__ void k_gat_edge1(const int* __restrict__ ei, const float* __restrict__ als,
                            const float* __restrict__ ald, bf16* __restrict__ ex,
                            float* __restrict__ denom)
{
    const int idx = blockIdx.x*blockDim.x + threadIdx.x;
    if (idx >= NETOT*NHEADS) return;
    const int e = idx >> 2, hd = idx & 3;
    int src, dst; bool drop;
    edge_decode(ei, e, src, dst, drop);
    if (drop){ ex[idx] = f2b(0.f); return; }
    float a = als[src*NHEADS + hd] + ald[dst*NHEADS + hd];
    a = a > 0.f ? a : 0.2f*a;
    const bf16 vb = f2b(__expf(a));
    ex[idx] = vb;
    atomicAdd(&denom[dst*NHEADS + hd], b2f(vb));
}

__global__ void k_gat_agg1(const int* __restrict__ ei, const bf16* __restrict__ ex,
                           const float* __restrict__ denom, const bf16* __restrict__ hw,
                           float* __restrict__ agg)
{
    const int t = blockIdx.x*blockDim.x + threadIdx.x;   // NETOT*128
    const int e = t >> 7, c = t & 127;
    if (e >= NETOT) return;
    const float x = b2f(ex[e*NHEADS + (c>>5)]);
    if (x == 0.f) return;
    int src, dst; bool drop;
    edge_decode(ei, e, src, dst, drop);
    const float w = x / denom[dst*NHEADS + (c>>5)];
    atomicAdd(&agg[(size_t)dst*HID + c], w * b2f(hw[(size_t)src*HID + c]));
}

__global__ void k_gat1_fin(const float* __restrict__ agg, const float* __restrict__ bias,
                           bf16* __restrict__ g1)
{
    const int t = blockIdx.x*blockDim.x + threadIdx.x;
    if (t >= NNODE*HID) return;
    const float v = agg[t] + bias[t & 127];
    g1[t] = f2b(v > 0.f ? v : expm1f(v));    // elu
}

__global__ void k_gat2_lin(const bf16* __restrict__ g1, const float* __restrict__ W,
                           const float* __restrict__ asrc, const float* __restrict__ adst,
                           bf16* __restrict__ hw2, float* __restrict__ al2s, float* __restrict__ al2d)
{
    const int nid = blockIdx.x, c = threadIdx.x;    // 64 threads = 1 wave
    __shared__ float hr[HID];
    hr[c] = b2f(g1[(size_t)nid*HID + c]);
    hr[c+64] = b2f(g1[(size_t)nid*HID + c + 64]);
    __syncthreads();
    float a = 0.f;
    for (int k = 0; k < HID; ++k) a += hr[k]*W[k*OUTCH + c];
    hw2[(size_t)nid*OUTCH + c] = f2b(a);
    float s1 = a*asrc[c], s2 = a*adst[c];
    #pragma unroll
    for (int off = 32; off > 0; off >>= 1){
        s1 += __shfl_down(s1, off);
        s2 += __shfl_down(s2, off);
    }
    if (c == 0){ al2s[nid] = s1; al2d[nid] = s2; }
}

__global__ void k_gat_edge2(const int* __restrict__ ei, const float* __restrict__ als,
                            const float* __restrict__ ald, bf16* __restrict__ ex,
                            float* __restrict__ denom)
{
    const int e = blockIdx.x*blockDim.x + threadIdx.x;
    if (e >= NETOT) return;
    int src, dst; bool drop;
    edge_decode(ei, e, src, dst, drop);
    if (drop){ ex[e] = f2b(0.f); return; }
    float a = als[src] + ald[dst];
    a = a > 0.f ? a : 0.2f*a;
    const bf16 vb = f2b(__expf(a));
    ex[e] = vb;
    atomicAdd(&denom[dst], b2f(vb));
}

__global__ void k_gat_agg2(const int* __restrict__ ei, const bf16* __restrict__ ex,
                           const float* __restrict__ denom, const bf16* __restrict__ hw2,
                           float* __restrict__ agg)
{
    const int t = blockIdx.x*blockDim.x + threadIdx.x;   // NETOT*64
    const int e = t >> 6, c = t & 63;
    if (e >= NETOT) return;
    const float x = b2f(ex[e]);
    if (x == 0.f) return;
    int src, dst; bool drop;
    edge_decode(ei, e, src, dst, drop);
    const float w = x / denom[dst];
    atomicAdd(&agg[(size_t)dst*OUTCH + c], w * b2f(hw2[(size_t)src*OUTCH + c]));
}

__global__ void k_final(const float* __restrict__ agg2, const float* __restrict__ g2b,
                        const float* __restrict__ fw, const float* __restrict__ fb,
                        float* __restrict__ out)
{
    const int nid = blockIdx.x, c = threadIdx.x;    // 64
    __shared__ float g[OUTCH];
    g[c] = agg2[(size_t)nid*OUTCH + c] + g2b[c];
    __syncthreads();
    if (c < OUTF){
        float o = fb[c];
        for (int k = 0; k < OUTCH; ++k) o += g[k]*fw[k*OUTF + c];
        const int b = nid >> 11, n = nid & (NN-1);
        out[((size_t)b*OUTF + c)*NN + n] = o;
    }
}

// ---------------------------------------------------------------------------
extern "C" void kernel_launch(void* const* d_in, const int* in_sizes, int n_in,
                              void* d_out, int out_size, void* d_ws, size_t ws_size,
                              hipStream_t stream)
{
    const float* x    = (const float*)d_in[0];
    const int*  ei    = (const int*)d_in[1];
    const float* ln1g = (const float*)d_in[2];  const float* ln1b = (const float*)d_in[3];
    const float* t_wq = (const float*)d_in[4];  const float* t_bq = (const float*)d_in[5];
    const float* t_wk = (const float*)d_in[6];  const float* t_bk = (const float*)d_in[7];
    const float* t_wv = (const float*)d_in[8];  const float* t_bv = (const float*)d_in[9];
    const float* t_wo = (const float*)d_in[10]; const float* t_bo = (const float*)d_in[11];
    const float* skw  = (const float*)d_in[12]; const float* skb  = (const float*)d_in[13];
    const float* ln2g = (const float*)d_in[14]; const float* ln2b = (const float*)d_in[15];
    const float* s_wq = (const float*)d_in[16]; const float* s_bq = (const float*)d_in[17];
    const float* s_wk = (const float*)d_in[18]; const float* s_bk = (const float*)d_in[19];
    const float* s_wv = (const float*)d_in[20]; const float* s_bv = (const float*)d_in[21];
    const float* s_wo = (const float*)d_in[22]; const float* s_bo = (const float*)d_in[23];
    const float* ln3g = (const float*)d_in[24]; const float* ln3b = (const float*)d_in[25];
    const float* w1   = (const float*)d_in[26]; const float* b1   = (const float*)d_in[27];
    const float* w2   = (const float*)d_in[28]; const float* b2   = (const float*)d_in[29];
    const float* g1w  = (const float*)d_in[30];
    const float* g1as = (const float*)d_in[31]; const float* g1ad = (const float*)d_in[32];
    const float* g1b  = (const float*)d_in[33];
    const float* g2w  = (const float*)d_in[34];
    const float* g2as = (const float*)d_in[35]; const float* g2ad = (const float*)d_in[36];
    const float* g2b  = (const float*)d_in[37];
    const float* ffw  = (const float*)d_in[38]; const float* ffb  = (const float*)d_in[39];
    float* out = (float*)d_out;

    const size_t MiB = 1024u*1024u;
    const bool wide = ws_size >= 52*MiB;   // K(16)+V(16)+H1(16)+Hn(4)

    char* base = (char*)d_ws;
    bf16 *Kb, *Vb, *H1;
    float* Hn;
    char* gat_base;
    if (wide){
        Kb = (bf16*)(base + 0*MiB);        // 16 MiB (all 32 slices)
        Vb = (bf16*)(base + 16*MiB);       // 16 MiB
        H1 = (bf16*)(base + 32*MiB);       // 16 MiB
        Hn = (float*)(base + 48*MiB);      // 4 MiB
        gat_base = base;                   // aliases Kb/Vb (dead after attn)
    } else {
        H1 = (bf16*)(base + 0*MiB);        // 16 MiB
        Hn = (float*)(base + 16*MiB);      // 4 MiB
        Kb = (bf16*)(base + 20*MiB);       // 0.5 MiB (one slice)
        Vb = (bf16*)(base + 20*MiB + 512u*1024u);
        gat_base = base;                   // aliases H1 (dead after k_mix)
    }
    // GAT scratch (~12.9 MiB) inside gat_base
    char* w = gat_base;
    auto alloc = [&](size_t bytes){ void* p = (void*)w; w += (bytes + 255) & ~(size_t)255; return p; };
    bf16*  hw1  = (bf16*) alloc((size_t)NNODE*HID*sizeof(bf16));
    float* als1 = (float*)alloc((size_t)NNODE*NHEADS*sizeof(float));
    float* ald1 = (float*)alloc((size_t)NNODE*NHEADS*sizeof(float));
    bf16*  ex1  = (bf16*) alloc((size_t)NETOT*NHEADS*sizeof(bf16));
    float* den1 = (float*)alloc((size_t)NNODE*NHEADS*sizeof(float));
    float* agg1 = (float*)alloc((size_t)NNODE*HID*sizeof(float));
    bf16*  g1o  = (bf16*) alloc((size_t)NNODE*HID*sizeof(bf16));
    bf16*  hw2  = (bf16*) alloc((size_t)NNODE*OUTCH*sizeof(bf16));
    float* als2 = (float*)alloc((size_t)NNODE*sizeof(float));
    float* ald2 = (float*)alloc((size_t)NNODE*sizeof(float));
    bf16*  ex2  = (bf16*) alloc((size_t)NETOT*sizeof(bf16));
    float* den2 = (float*)alloc((size_t)NNODE*sizeof(float));
    float* agg2 = (float*)alloc((size_t)NNODE*OUTCH*sizeof(float));

    // ---- trunk ----
    if (wide){
        k_kv<<<PROWS, HID, 0, stream>>>(x, ln1g, ln1b, t_wk, t_bk, t_wv, t_bv, 0, Kb, Vb);
        k_attn_flash<<<dim3(NN/TQ, BM), 256, 0, stream>>>(x, Kb, Vb, ln1g, ln1b, t_wq, t_bq,
                                                          skw, skb, t_wo, t_bo, 0, H1);
    } else {
        for (int s = 0; s < BM; ++s){
            k_kv<<<NN, HID, 0, stream>>>(x, ln1g, ln1b, t_wk, t_bk, t_wv, t_bv, s*NN, Kb, Vb);
            k_attn_flash<<<dim3(NN/TQ, 1), 256, 0, stream>>>(x, Kb, Vb, ln1g, ln1b, t_wq, t_bq,
                                                             skw, skb, t_wo, t_bo, s, H1);
        }
    }
    k_mix<<<BB*NN, HID, 0, stream>>>(H1, ln2g, ln2b, s_wq, s_bq, s_wk, s_bk,
                                     s_wv, s_bv, s_wo, s_bo, ln3g, ln3b,
                                     w1, b1, w2, b2, Hn);

    // ---- GAT (accumulators zeroed after k_mix; region was dead/poisoned) ----
    hipMemsetAsync(den1, 0, (size_t)NNODE*NHEADS*sizeof(float), stream);
    hipMemsetAsync(agg1, 0, (size_t)NNODE*HID*sizeof(float), stream);
    hipMemsetAsync(den2, 0, (size_t)NNODE*sizeof(float), stream);
    hipMemsetAsync(agg2, 0, (size_t)NNODE*OUTCH*sizeof(float), stream);

    k_gat1_lin<<<NNODE, HID, 0, stream>>>(Hn, g1w, g1as, g1ad, hw1, als1, ald1);
    k_gat_edge1<<<(NETOT*NHEADS + 255)/256, 256, 0, stream>>>(ei, als1, ald1, ex1, den1);
    k_gat_agg1<<<(NETOT*HID)/256, 256, 0, stream>>>(ei, ex1, den1, hw1, agg1);
    k_gat1_fin<<<(NNODE*HID)/256, 256, 0, stream>>>(agg1, g1b, g1o);
    k_gat2_lin<<<NNODE, OUTCH, 0, stream>>>(g1o, g2w, g2as, g2ad, hw2, als2, ald2);
    k_gat_edge2<<<(NETOT + 255)/256, 256, 0, stream>>>(ei, als2, ald2, ex2, den2);
    k_gat_agg2<<<(NETOT*OUTCH)/256, 256, 0, stream>>>(ei, ex2, den2, hw2, agg2);
    k_final<<<NNODE, OUTCH, 0, stream>>>(agg2, g2b, ffw, ffb, out);
}